// Round 15
// baseline (363.586 us; speedup 1.0000x reference)
//
#include <hip/hip_runtime.h>

#define NN 100000
#define RR 3
#define EE 200000
#define HH 4
#define ETOT (RR * EE)
#define NB ((NN + 255) / 256)

typedef __attribute__((ext_vector_type(8))) short bf16x8;
typedef __attribute__((ext_vector_type(4))) float f32x4;

__device__ __forceinline__ int clampi(int v, int lo, int hi) {
  return v < lo ? lo : (v > hi ? hi : v);
}

// split fp32 -> bf16 hi + bf16 lo (RNE both)
__device__ __forceinline__ void split2(float v, ushort& h, ushort& l) {
  uint u = __float_as_uint(v);
  uint hb = (u + 0x7FFFu + ((u >> 16) & 1u)) >> 16;
  float fh = __uint_as_float(hb << 16);
  float r = v - fh;
  uint ur = __float_as_uint(r);
  uint lb = (ur + 0x7FFFu + ((ur >> 16) & 1u)) >> 16;
  h = (ushort)hb; l = (ushort)lb;
}

__device__ __forceinline__ ushort f2bf(float v) {
  uint u = __float_as_uint(v);
  return (ushort)((u + 0x7FFFu + ((u >> 16) & 1u)) >> 16);
}

// ---------------- fp32 -> bf16 (hi only) ----------------
__global__ __launch_bounds__(256) void to_bf16(
    const float* __restrict__ A, ushort* __restrict__ Ah, int total8)
{
  int idx = blockIdx.x * 256 + threadIdx.x;
  if (idx >= total8) return;
  const float4* ap = (const float4*)(A + (size_t)idx * 8);
  float4 a0 = ap[0], a1 = ap[1];
  const float v[8] = {a0.x, a0.y, a0.z, a0.w, a1.x, a1.y, a1.z, a1.w};
  ushort h[8];
  #pragma unroll
  for (int i = 0; i < 8; ++i) h[i] = f2bf(v[i]);
  *(uint4*)(Ah + (size_t)idx * 8) = *(const uint4*)h;
}

// ---------------- pure-bf16 persistent-A GEMM (1 MFMA/tile) ----------------
template<int KT>   // K = KT*32
__global__ __launch_bounds__(256) void gemm_bf1(
    const ushort* __restrict__ Ah, const ushort* __restrict__ Bth,
    int M, int NTOT,
    ushort* __restrict__ kb, int nk, ushort* __restrict__ vb,
    ushort* __restrict__ qb, int nq, int reluq)
{
  constexpr int K = KT * 32;
  constexpr int LDB = KT * 16 + 4;
  __shared__ uint Bs[2][64 * LDB];
  const int tid = threadIdx.x;
  const int m0 = blockIdx.x * 128;
  const int lane = tid & 63, wv = tid >> 6;
  const int rbase = m0 + wv * 32 + (lane & 15);
  const int kof = (lane >> 4) * 8;

  bf16x8 a[2][KT];
  #pragma unroll
  for (int m = 0; m < 2; ++m) {
    const int row = rbase + m * 16;
    #pragma unroll
    for (int kt = 0; kt < KT; ++kt) {
      uint4 u = make_uint4(0, 0, 0, 0);
      if (row < M) u = *(const uint4*)(Ah + (size_t)row * K + kt * 32 + kof);
      a[m][kt] = *reinterpret_cast<bf16x8*>(&u);
    }
  }

  auto stage = [&](int cb, int b) {
    const int c = tid >> 2, kq = tid & 3;
    if (kq * 32 < K) {
      const uint4* s = (const uint4*)(Bth + (size_t)(cb + c) * K + kq * 32);
      uint4* d = (uint4*)&Bs[b][c * LDB + kq * 16];
      #pragma unroll
      for (int q = 0; q < 4; ++q) d[q] = s[q];
    }
  };
  stage(0, 0);
  __syncthreads();
  int buf = 0;

  for (int cb = 0; cb < NTOT; cb += 64) {
    if (cb + 64 < NTOT) stage(cb + 64, buf ^ 1);

    f32x4 acc[2][4];
    #pragma unroll
    for (int m = 0; m < 2; ++m)
      #pragma unroll
      for (int n = 0; n < 4; ++n) acc[m][n] = (f32x4){0.f, 0.f, 0.f, 0.f};

    #pragma unroll
    for (int kt = 0; kt < KT; ++kt) {
      #pragma unroll
      for (int n = 0; n < 4; ++n) {
        const int boff = (n * 16 + (lane & 15)) * LDB + kt * 16 + (lane >> 4) * 4;
        uint4 u = *(const uint4*)&Bs[buf][boff];
        bf16x8 b8 = *reinterpret_cast<bf16x8*>(&u);
        acc[0][n] = __builtin_amdgcn_mfma_f32_16x16x32_bf16(a[0][kt], b8, acc[0][n], 0, 0, 0);
        acc[1][n] = __builtin_amdgcn_mfma_f32_16x16x32_bf16(a[1][kt], b8, acc[1][n], 0, 0, 0);
      }
    }

    ushort* ob; int stride, cbase, relu = 0;
    if (cb < nk)            { ob = kb; stride = nk; cbase = cb; }
    else if (cb < 2 * nk)   { ob = vb; stride = nk; cbase = cb - nk; }
    else                    { ob = qb; stride = nq; cbase = cb - 2 * nk; relu = reluq; }
    #pragma unroll
    for (int m = 0; m < 2; ++m) {
      const int rw = m0 + wv * 32 + m * 16 + (lane >> 4) * 4;
      #pragma unroll
      for (int n = 0; n < 4; ++n) {
        const int col = cbase + n * 16 + (lane & 15);
        #pragma unroll
        for (int j = 0; j < 4; ++j) {
          if (rw + j < M) {
            float o = acc[m][n][j];
            if (relu) o = fmaxf(o, 0.f);
            ob[(size_t)(rw + j) * stride + col] = f2bf(o);
          }
        }
      }
    }
    __syncthreads();
    buf ^= 1;
  }
}

// ---------------- split-bf16 persistent-A GEMM (3 MFMA/tile), fp32 out -------
template<int KT>
__global__ __launch_bounds__(256) void gemm_sp3(
    const ushort* __restrict__ Ah, const ushort* __restrict__ Al,
    const ushort* __restrict__ Bth, const ushort* __restrict__ Btl,
    int M, int NTOT, float* __restrict__ of)
{
  constexpr int K = KT * 32;
  constexpr int LDB = KT * 16 + 4;
  __shared__ uint Bh[64 * LDB];
  __shared__ uint Bl[64 * LDB];
  const int tid = threadIdx.x;
  const int m0 = blockIdx.x * 128;
  const int lane = tid & 63, wv = tid >> 6;
  const int rbase = m0 + wv * 32 + (lane & 15);
  const int kof = (lane >> 4) * 8;

  bf16x8 ah[2][KT], al[2][KT];
  #pragma unroll
  for (int m = 0; m < 2; ++m) {
    const int row = rbase + m * 16;
    #pragma unroll
    for (int kt = 0; kt < KT; ++kt) {
      uint4 uh = make_uint4(0, 0, 0, 0), ul = make_uint4(0, 0, 0, 0);
      if (row < M) {
        uh = *(const uint4*)(Ah + (size_t)row * K + kt * 32 + kof);
        ul = *(const uint4*)(Al + (size_t)row * K + kt * 32 + kof);
      }
      ah[m][kt] = *reinterpret_cast<bf16x8*>(&uh);
      al[m][kt] = *reinterpret_cast<bf16x8*>(&ul);
    }
  }

  for (int cb = 0; cb < NTOT; cb += 64) {
    {
      const int c = tid >> 2, kq = tid & 3;
      if (kq * 32 < K) {
        const uint4* sh = (const uint4*)(Bth + (size_t)(cb + c) * K + kq * 32);
        const uint4* sl = (const uint4*)(Btl + (size_t)(cb + c) * K + kq * 32);
        uint4* dh = (uint4*)&Bh[c * LDB + kq * 16];
        uint4* dl = (uint4*)&Bl[c * LDB + kq * 16];
        #pragma unroll
        for (int q = 0; q < 4; ++q) { dh[q] = sh[q]; dl[q] = sl[q]; }
      }
    }
    __syncthreads();

    f32x4 acc[2][4];
    #pragma unroll
    for (int m = 0; m < 2; ++m)
      #pragma unroll
      for (int n = 0; n < 4; ++n) acc[m][n] = (f32x4){0.f, 0.f, 0.f, 0.f};

    #pragma unroll
    for (int kt = 0; kt < KT; ++kt) {
      #pragma unroll
      for (int n = 0; n < 4; ++n) {
        const int boff = (n * 16 + (lane & 15)) * LDB + kt * 16 + (lane >> 4) * 4;
        uint4 uh = *(const uint4*)&Bh[boff];
        uint4 ul = *(const uint4*)&Bl[boff];
        bf16x8 bh = *reinterpret_cast<bf16x8*>(&uh);
        bf16x8 bl = *reinterpret_cast<bf16x8*>(&ul);
        #pragma unroll
        for (int m = 0; m < 2; ++m) {
          acc[m][n] = __builtin_amdgcn_mfma_f32_16x16x32_bf16(ah[m][kt], bh, acc[m][n], 0, 0, 0);
          acc[m][n] = __builtin_amdgcn_mfma_f32_16x16x32_bf16(ah[m][kt], bl, acc[m][n], 0, 0, 0);
          acc[m][n] = __builtin_amdgcn_mfma_f32_16x16x32_bf16(al[m][kt], bh, acc[m][n], 0, 0, 0);
        }
      }
    }

    #pragma unroll
    for (int m = 0; m < 2; ++m) {
      const int rw = m0 + wv * 32 + m * 16 + (lane >> 4) * 4;
      #pragma unroll
      for (int n = 0; n < 4; ++n) {
        const int col = cb + n * 16 + (lane & 15);
        #pragma unroll
        for (int j = 0; j < 4; ++j)
          if (rw + j < M) of[(size_t)(rw + j) * NTOT + col] = acc[m][n][j];
      }
    }
    __syncthreads();
  }
}

// ---------------- plain weight -> transposed split-bf16 ----------------
__global__ __launch_bounds__(256) void convt(
    const float* __restrict__ W, ushort* __restrict__ Th, ushort* __restrict__ Tl,
    int K, int N)
{
  int idx = blockIdx.x * 256 + threadIdx.x;
  if (idx >= K * N) return;
  int n = idx / K, k = idx % K;
  ushort h, l; split2(W[(size_t)k * N + n], h, l);
  Th[(size_t)n * K + k] = h;
  Tl[(size_t)n * K + k] = l;
}

// ---------------- weight-space fusion -> transposed split-bf16 ----------------
// If prior != nullptr, scale column (r,h,*) by prior[r*HH+h]*scale (folds the
// softmax prior/sqrt(dh) into the kA weights -> removed from edge hot loop).
__global__ __launch_bounds__(256) void build_wT(
    const float* __restrict__ W, const float* __restrict__ T,
    ushort* __restrict__ Oh, ushort* __restrict__ Ol, int F, int D, int dh,
    const float* __restrict__ prior, float scale)
{
  const int cols = RR * D;
  int idx = blockIdx.x * 256 + threadIdx.x;
  if (idx >= F * cols) return;
  int i = idx / cols, c = idx % cols;
  int r = c / D, gf = c % D;
  int h = gf / dh, f = gf % dh;
  const float* w = W + (size_t)i * D + h * dh;
  const float* t = T + ((size_t)(r * HH + h) * dh) * dh + f;
  float s = 0.f;
  for (int d = 0; d < dh; ++d) s = fmaf(w[d], t[(size_t)d * dh], s);
  if (prior) s *= prior[r * HH + h] * scale;
  ushort hh, ll; split2(s, hh, ll);
  Oh[(size_t)c * F + i] = hh;
  Ol[(size_t)c * F + i] = ll;
}

// ---------------- CSR build ----------------
__global__ __launch_bounds__(256) void zero_i32(int* __restrict__ p, int n)
{
  int i = blockIdx.x * 256 + threadIdx.x;
  if (i < n) p[i] = 0;
}

__global__ __launch_bounds__(256) void csr_count(
    const int* __restrict__ EI, int* __restrict__ cnt)
{
  int idx = blockIdx.x * 256 + threadIdx.x;
  if (idx >= ETOT) return;
  int r = idx / EE, e = idx % EE;
  int dst = clampi(EI[(size_t)r * 2 * EE + EE + e], 0, NN - 1);
  atomicAdd(&cnt[dst], 1);
}

__global__ __launch_bounds__(256) void scan_intra(
    int* __restrict__ arr, int* __restrict__ blksum)
{
  __shared__ int s[256];
  const int t = threadIdx.x;
  const int i = blockIdx.x * 256 + t;
  int v = (i < NN) ? arr[i] : 0;
  s[t] = v;
  __syncthreads();
  #pragma unroll
  for (int off = 1; off < 256; off <<= 1) {
    int x = (t >= off) ? s[t - off] : 0;
    __syncthreads();
    s[t] += x;
    __syncthreads();
  }
  if (i < NN) arr[i] = s[t] - v;        // exclusive
  if (t == 255) blksum[blockIdx.x] = s[255];
}

__global__ __launch_bounds__(256) void scan_mid(
    const int* __restrict__ blksum, int* __restrict__ blkoff)
{
  __shared__ int s[256];
  __shared__ int carry;
  const int t = threadIdx.x;
  if (t == 0) carry = 0;
  __syncthreads();
  for (int base = 0; base < NB; base += 256) {
    const int i = base + t;
    int v = (i < NB) ? blksum[i] : 0;
    s[t] = v;
    __syncthreads();
    #pragma unroll
    for (int off = 1; off < 256; off <<= 1) {
      int x = (t >= off) ? s[t - off] : 0;
      __syncthreads();
      s[t] += x;
      __syncthreads();
    }
    if (i < NB) blkoff[i] = carry + s[t] - v;   // global exclusive
    __syncthreads();
    if (t == 255) carry += s[255];
    __syncthreads();
  }
}

__global__ __launch_bounds__(256) void scan_add(
    int* __restrict__ arr, const int* __restrict__ blkoff,
    int* __restrict__ rowptr, int* __restrict__ cursor)
{
  int i = blockIdx.x * 256 + threadIdx.x;
  if (i < NN) {
    int v = arr[i] + blkoff[i >> 8];
    rowptr[i] = v;
    cursor[i] = v;
  }
  if (i == NN) rowptr[NN] = ETOT;
}

__global__ __launch_bounds__(256) void csr_scatter(
    const int* __restrict__ EI, int* __restrict__ cursor,
    int* __restrict__ srcrel)
{
  int idx = blockIdx.x * 256 + threadIdx.x;
  if (idx >= ETOT) return;
  int r = idx / EE, e = idx % EE;
  int src = clampi(EI[(size_t)r * 2 * EE + e], 0, NN - 1);
  int dst = clampi(EI[(size_t)r * 2 * EE + EE + e], 0, NN - 1);
  int pos = atomicAdd(&cursor[dst], 1);
  pos = clampi(pos, 0, ETOT - 1);
  srcrel[pos] = src | (r << 24);
}

// ---------------- fused per-node score+softmax+aggregate (edge-slot waves) ----
// kb/vb planar bf16 [N][RR*D] (prior/scale folded into kb); qb planar bf16.
// One node per WAVE; 64 lanes = ES edge slots x (D/4) lanes; lane covers 4
// features (uint2 = 8B loads). Slots process DIFFERENT edges of the SAME node
// -> j0/j1 wave-uniform, no divergence. 3-level (L1) / 2-level (L2) shfl per
// edge batch; cross-slot combine once per node at loop exit.
// Clamps on srcrel-derived indices are load-bearing (r5/6, r12/13) — keep.
template<int D, int DH>
__global__ __launch_bounds__(256) void node_fused(
    const ushort* __restrict__ kb, const ushort* __restrict__ vb,
    const ushort* __restrict__ qb,
    const int* __restrict__ rowptr, const int* __restrict__ srcrel,
    ushort* __restrict__ agh, ushort* __restrict__ agl)
{
  constexpr int LPS = D / 4;        // lanes per edge slot (32 / 16)
  constexpr int ES  = 64 / LPS;     // edge slots per wave (2 / 4)
  constexpr int SUB = DH / 4;       // lanes per head in a slot (8 / 4)
  const int lane = threadIdx.x & 63;
  const int wv = threadIdx.x >> 6;
  const int n = blockIdx.x * 4 + wv;
  if (n >= NN) return;
  const int slot = lane / LPS;
  const int sl   = lane % LPS;      // features [4sl, 4sl+4)
  const uint2 qu = *(const uint2*)&qb[(size_t)n * D + sl * 4];
  const float q0 = __uint_as_float(qu.x << 16);
  const float q1 = __uint_as_float(qu.x & 0xFFFF0000u);
  const float q2 = __uint_as_float(qu.y << 16);
  const float q3 = __uint_as_float(qu.y & 0xFFFF0000u);
  const int j0 = clampi(rowptr[n], 0, ETOT);
  const int j1 = clampi(rowptr[n + 1], j0, ETOT);
  float a0 = 0.f, a1 = 0.f, a2 = 0.f, a3 = 0.f, den = 0.f;

  for (int jb = j0; jb < j1; jb += ES) {
    const int j = jb + slot;
    const bool valid = j < j1;
    const int jj = clampi(valid ? j : j0, 0, ETOT - 1);  // invalid -> re-read j0 (hot)
    const int w = srcrel[jj];
    const int si = clampi(w & 0xFFFFFF, 0, NN - 1);
    const int r  = clampi(w >> 24, 0, RR - 1);
    const size_t base = (size_t)si * (RR * D) + r * D + sl * 4;
    const uint2 ku = *(const uint2*)&kb[base];
    const uint2 vu = *(const uint2*)&vb[base];
    float s =        __uint_as_float(ku.x << 16)          * q0;
    s = fmaf(__uint_as_float(ku.x & 0xFFFF0000u), q1, s);
    s = fmaf(__uint_as_float(ku.y << 16),         q2, s);
    s = fmaf(__uint_as_float(ku.y & 0xFFFF0000u), q3, s);
    #pragma unroll
    for (int off = SUB / 2; off >= 1; off >>= 1) s += __shfl_xor(s, off, 64);
    const float ex = valid ? __expf(s) : 0.f;   // prior*scale already in kb
    den += ex;
    a0 = fmaf(ex, __uint_as_float(vu.x << 16),          a0);
    a1 = fmaf(ex, __uint_as_float(vu.x & 0xFFFF0000u),  a1);
    a2 = fmaf(ex, __uint_as_float(vu.y << 16),          a2);
    a3 = fmaf(ex, __uint_as_float(vu.y & 0xFFFF0000u),  a3);
  }

  // cross-slot combine (slots hold partial sums for the SAME node)
  #pragma unroll
  for (int off = LPS; off < 64; off <<= 1) {
    den += __shfl_xor(den, off, 64);
    a0 += __shfl_xor(a0, off, 64);
    a1 += __shfl_xor(a1, off, 64);
    a2 += __shfl_xor(a2, off, 64);
    a3 += __shfl_xor(a3, off, 64);
  }

  if (slot == 0) {
    const float inv = 1.f / (den + 1e-9f);
    const float o0 = a0 * inv, o1 = a1 * inv, o2 = a2 * inv, o3 = a3 * inv;
    if (agl) {
      ushort h0, l0, h1, l1, h2, l2, h3, l3;
      split2(o0, h0, l0); split2(o1, h1, l1);
      split2(o2, h2, l2); split2(o3, h3, l3);
      uint2 ho = make_uint2((uint)h0 | ((uint)h1 << 16), (uint)h2 | ((uint)h3 << 16));
      uint2 lo = make_uint2((uint)l0 | ((uint)l1 << 16), (uint)l2 | ((uint)l3 << 16));
      *(uint2*)&agh[(size_t)n * D + sl * 4] = ho;
      *(uint2*)&agl[(size_t)n * D + sl * 4] = lo;
    } else {
      uint2 ho = make_uint2((uint)f2bf(o0) | ((uint)f2bf(o1) << 16),
                            (uint)f2bf(o2) | ((uint)f2bf(o3) << 16));
      *(uint2*)&agh[(size_t)n * D + sl * 4] = ho;
    }
  }
}

extern "C" void kernel_launch(void* const* d_in, const int* in_sizes, int n_in,
                              void* d_out, int out_size, void* d_ws, size_t ws_size,
                              hipStream_t stream)
{
  const float* x   = (const float*)d_in[0];
  const int*   EI  = (const int*)  d_in[1];
  const float* Wk1 = (const float*)d_in[2];
  const float* Wq1 = (const float*)d_in[3];
  const float* Wv1 = (const float*)d_in[4];
  const float* A1  = (const float*)d_in[5];
  const float* M1  = (const float*)d_in[6];
  const float* P1  = (const float*)d_in[7];
  const float* Wo1 = (const float*)d_in[8];
  const float* Wk2 = (const float*)d_in[9];
  const float* Wq2 = (const float*)d_in[10];
  const float* Wv2 = (const float*)d_in[11];
  const float* A2  = (const float*)d_in[12];
  const float* M2  = (const float*)d_in[13];
  const float* P2  = (const float*)d_in[14];
  const float* Wo2 = (const float*)d_in[15];
  float* out = (float*)d_out;

  float* ws = (float*)d_ws;
  const size_t nd = (size_t)NN * 128;
  // ---- layout identical to round 14 (proven) ----
  ushort* xh   = (ushort*)ws;
  ushort* agh  = xh;
  ushort* qb2  = (ushort*)ws;                      // [0, nd/4)
  ushort* ag2h = (ushort*)(ws + nd / 4);           // [nd/4, nd/2)
  ushort* qb1  = (ushort*)(ws + nd / 2);           // [nd/2, nd)
  ushort* ag2l = (ushort*)(ws + nd / 2);           // [nd/2, 3nd/4) (qb1 dead)
  ushort* kb   = (ushort*)(ws + nd);
  ushort* vb   = (ushort*)(ws + 5 * nd / 2);
  ushort* Hbh  = (ushort*)(ws + 4 * nd);
  ushort* WBth = (ushort*)(ws + 5 * nd);
  ushort* WBtl = WBth + 896 * 128;
  int* ints   = (int*)(WBtl + 896 * 128);
  int* rowptr = ints;              // NN+1
  int* cursor = rowptr + NN + 1;   // NN
  int* blks   = cursor + NN;       // 2*NB
  int* srcrel = blks + 2 * NB;     // ETOT (src | r<<24, dst-sorted)

  const size_t need_bytes = (5 * nd + 114688) * 4 +
      ((size_t)(NN + 1) + NN + 2 * NB + ETOT) * 4;
  if (ws_size < need_bytes) return;   // visible absmax failure, not a fault

  dim3 blk(256);
  const int GB = (NN + 127) / 128;    // 782 row-blocks
  const int NFB = (NN + 3) / 4;       // node_fused blocks (1 node/wave now)

  // ---------- prep: x -> bf16, L1 concat weights (prior folded into kA) ------
  to_bf16<<<dim3((NN * 128 / 8 + 255) / 256), blk, 0, stream>>>(x, xh, NN * 128 / 8);
  build_wT<<<dim3(192), blk, 0, stream>>>(Wk1, A1, WBth, WBtl, 128, 128, 32,
                                          P1, 0.17677669529663687f);
  build_wT<<<dim3(192), blk, 0, stream>>>(Wv1, M1, WBth + 384 * 128, WBtl + 384 * 128,
                                          128, 128, 32, (const float*)nullptr, 1.f);
  convt<<<dim3(64), blk, 0, stream>>>(Wq1, WBth + 768 * 128, WBtl + 768 * 128, 128, 128);

  // ---------- Layer 1: ONE bf16 GEMM for kA|vM|q ----------
  gemm_bf1<4><<<dim3(GB), blk, 0, stream>>>(xh, WBth, NN, 896, kb, 384, vb, qb1, 128, 0);

  // ---------- CSR build (shared by both layers) ----------
  zero_i32<<<dim3(NB), blk, 0, stream>>>(cursor, NN);
  csr_count<<<dim3((ETOT + 255) / 256), blk, 0, stream>>>(EI, cursor);
  scan_intra<<<dim3(NB), blk, 0, stream>>>(cursor, blks);
  scan_mid<<<dim3(1), blk, 0, stream>>>(blks, blks + NB);
  scan_add<<<dim3(NB), blk, 0, stream>>>(cursor, blks + NB, rowptr, cursor);
  csr_scatter<<<dim3((ETOT + 255) / 256), blk, 0, stream>>>(EI, cursor, srcrel);

  // ---------- Layer 1 edge + output (agh overwrites dead xh) ----------
  node_fused<128, 32><<<dim3(NFB), blk, 0, stream>>>(
      kb, vb, qb1, rowptr, srcrel, agh, (ushort*)nullptr);
  convt<<<dim3(64), blk, 0, stream>>>(Wo1, WBth, WBtl, 128, 128);
  gemm_bf1<4><<<dim3(GB), blk, 0, stream>>>(agh, WBth, NN, 128,
                                            (ushort*)nullptr, 0, (ushort*)nullptr,
                                            Hbh, 128, 1);   // relu

  // ---------- Layer 2: ONE bf16 GEMM for kA2|vM2|q2 ----------
  build_wT<<<dim3(96), blk, 0, stream>>>(Wk2, A2, WBth, WBtl, 128, 64, 16,
                                         P2, 0.25f);
  build_wT<<<dim3(96), blk, 0, stream>>>(Wv2, M2, WBth + 192 * 128, WBtl + 192 * 128,
                                         128, 64, 16, (const float*)nullptr, 1.f);
  convt<<<dim3(32), blk, 0, stream>>>(Wq2, WBth + 384 * 128, WBtl + 384 * 128, 128, 64);
  gemm_bf1<4><<<dim3(GB), blk, 0, stream>>>(Hbh, WBth, NN, 448, kb, 192, vb, qb2, 64, 0);

  node_fused<64, 16><<<dim3(NFB), blk, 0, stream>>>(
      kb, vb, qb2, rowptr, srcrel, ag2h, ag2l);
  convt<<<dim3(16), blk, 0, stream>>>(Wo2, WBth, WBtl, 64, 64);
  gemm_sp3<2><<<dim3(GB), blk, 0, stream>>>(ag2h, ag2l, WBth, WBtl, NN, 64, out);
}

// Round 16
// 303.595 us; speedup vs baseline: 1.1976x; 1.1976x over previous
//
#include <hip/hip_runtime.h>

#define NN 100000
#define RR 3
#define EE 200000
#define HH 4
#define ETOT (RR * EE)
#define NB ((NN + 255) / 256)

typedef __attribute__((ext_vector_type(8))) short bf16x8;
typedef __attribute__((ext_vector_type(4))) float f32x4;

__device__ __forceinline__ int clampi(int v, int lo, int hi) {
  return v < lo ? lo : (v > hi ? hi : v);
}

__device__ __forceinline__ void split2(float v, ushort& h, ushort& l) {
  uint u = __float_as_uint(v);
  uint hb = (u + 0x7FFFu + ((u >> 16) & 1u)) >> 16;
  float fh = __uint_as_float(hb << 16);
  float r = v - fh;
  uint ur = __float_as_uint(r);
  uint lb = (ur + 0x7FFFu + ((ur >> 16) & 1u)) >> 16;
  h = (ushort)hb; l = (ushort)lb;
}

__device__ __forceinline__ ushort f2bf(float v) {
  uint u = __float_as_uint(v);
  return (ushort)((u + 0x7FFFu + ((u >> 16) & 1u)) >> 16);
}

// ---------------- prep bodies (device) ----------------
__device__ __forceinline__ void to_bf16_body(
    const float* __restrict__ A, ushort* __restrict__ Ah, int blk, int total8)
{
  int idx = blk * 256 + threadIdx.x;
  if (idx >= total8) return;
  const float4* ap = (const float4*)(A + (size_t)idx * 8);
  float4 a0 = ap[0], a1 = ap[1];
  const float v[8] = {a0.x, a0.y, a0.z, a0.w, a1.x, a1.y, a1.z, a1.w};
  ushort h[8];
  #pragma unroll
  for (int i = 0; i < 8; ++i) h[i] = f2bf(v[i]);
  *(uint4*)(Ah + (size_t)idx * 8) = *(const uint4*)h;
}

__device__ __forceinline__ void build_wT_body(
    const float* __restrict__ W, const float* __restrict__ T,
    ushort* __restrict__ Oh, ushort* __restrict__ Ol, int F, int D, int dh,
    const float* __restrict__ prior, float scale, int blk)
{
  const int cols = RR * D;
  int idx = blk * 256 + threadIdx.x;
  if (idx >= F * cols) return;
  int i = idx / cols, c = idx % cols;
  int r = c / D, gf = c % D;
  int h = gf / dh, f = gf % dh;
  const float* w = W + (size_t)i * D + h * dh;
  const float* t = T + ((size_t)(r * HH + h) * dh) * dh + f;
  float s = 0.f;
  for (int d = 0; d < dh; ++d) s = fmaf(w[d], t[(size_t)d * dh], s);
  if (prior) s *= prior[r * HH + h] * scale;
  ushort hh, ll; split2(s, hh, ll);
  Oh[(size_t)c * F + i] = hh;
  Ol[(size_t)c * F + i] = ll;
}

__device__ __forceinline__ void convt_body(
    const float* __restrict__ W, ushort* __restrict__ Th, ushort* __restrict__ Tl,
    int K, int N, int blk)
{
  int idx = blk * 256 + threadIdx.x;
  if (idx >= K * N) return;
  int n = idx / K, k = idx % K;
  ushort h, l; split2(W[(size_t)k * N + n], h, l);
  Th[(size_t)n * K + k] = h;
  Tl[(size_t)n * K + k] = l;
}

// ---------------- prep_all: x->bf16, cursor zero, ALL weight builds ----------
// WB column map: [0,384) kA1 | [384,768) vM1 | [768,896) q1 | [896,1024) Wo1 |
// [1024,1216) kA2 | [1216,1408) vM2 | [1408,1472) q2 | [1472,1536) Wo2
__global__ __launch_bounds__(256) void prep_all(
    const float* __restrict__ x, ushort* __restrict__ xh,
    const float* __restrict__ Wk1, const float* __restrict__ A1, const float* __restrict__ P1,
    const float* __restrict__ Wv1, const float* __restrict__ M1,
    const float* __restrict__ Wq1, const float* __restrict__ Wo1,
    const float* __restrict__ Wk2, const float* __restrict__ A2, const float* __restrict__ P2,
    const float* __restrict__ Wv2, const float* __restrict__ M2,
    const float* __restrict__ Wq2, const float* __restrict__ Wo2,
    ushort* __restrict__ WBth, ushort* __restrict__ WBtl, int* __restrict__ cursor)
{
  int b = blockIdx.x;
  if (b < 6250) { to_bf16_body(x, xh, b, NN * 128 / 8); return; }
  b -= 6250;
  if (b < NB) { int i = b * 256 + threadIdx.x; if (i < NN) cursor[i] = 0; return; }
  b -= NB;
  if (b < 192) { build_wT_body(Wk1, A1, WBth, WBtl, 128, 128, 32, P1, 0.17677669529663687f, b); return; }
  b -= 192;
  if (b < 192) { build_wT_body(Wv1, M1, WBth + 384 * 128, WBtl + 384 * 128, 128, 128, 32, (const float*)0, 1.f, b); return; }
  b -= 192;
  if (b < 64) { convt_body(Wq1, WBth + 768 * 128, WBtl + 768 * 128, 128, 128, b); return; }
  b -= 64;
  if (b < 64) { convt_body(Wo1, WBth + 896 * 128, WBtl + 896 * 128, 128, 128, b); return; }
  b -= 64;
  if (b < 96) { build_wT_body(Wk2, A2, WBth + 1024 * 128, WBtl + 1024 * 128, 128, 64, 16, P2, 0.25f, b); return; }
  b -= 96;
  if (b < 96) { build_wT_body(Wv2, M2, WBth + 1216 * 128, WBtl + 1216 * 128, 128, 64, 16, (const float*)0, 1.f, b); return; }
  b -= 96;
  if (b < 32) { convt_body(Wq2, WBth + 1408 * 128, WBtl + 1408 * 128, 128, 64, b); return; }
  b -= 32;
  if (b < 16) { convt_body(Wo2, WBth + 1472 * 128, WBtl + 1472 * 128, 64, 64, b); return; }
}
#define PREP_BLOCKS (6250 + NB + 192 + 192 + 64 + 64 + 96 + 96 + 32 + 16)

// ---------------- pure-bf16 persistent-A GEMM (1 MFMA/tile) ----------------
template<int KT>   // K = KT*32
__global__ __launch_bounds__(256) void gemm_bf1(
    const ushort* __restrict__ Ah, const ushort* __restrict__ Bth,
    int M, int NTOT,
    ushort* __restrict__ kb, int nk, ushort* __restrict__ vb,
    ushort* __restrict__ qb, int nq, int reluq)
{
  constexpr int K = KT * 32;
  constexpr int LDB = KT * 16 + 4;
  __shared__ uint Bs[2][64 * LDB];
  const int tid = threadIdx.x;
  const int m0 = blockIdx.x * 128;
  const int lane = tid & 63, wv = tid >> 6;
  const int rbase = m0 + wv * 32 + (lane & 15);
  const int kof = (lane >> 4) * 8;

  bf16x8 a[2][KT];
  #pragma unroll
  for (int m = 0; m < 2; ++m) {
    const int row = rbase + m * 16;
    #pragma unroll
    for (int kt = 0; kt < KT; ++kt) {
      uint4 u = make_uint4(0, 0, 0, 0);
      if (row < M) u = *(const uint4*)(Ah + (size_t)row * K + kt * 32 + kof);
      a[m][kt] = *reinterpret_cast<bf16x8*>(&u);
    }
  }

  auto stage = [&](int cb, int b) {
    const int c = tid >> 2, kq = tid & 3;
    if (kq * 32 < K) {
      const uint4* s = (const uint4*)(Bth + (size_t)(cb + c) * K + kq * 32);
      uint4* d = (uint4*)&Bs[b][c * LDB + kq * 16];
      #pragma unroll
      for (int q = 0; q < 4; ++q) d[q] = s[q];
    }
  };
  stage(0, 0);
  __syncthreads();
  int buf = 0;

  for (int cb = 0; cb < NTOT; cb += 64) {
    if (cb + 64 < NTOT) stage(cb + 64, buf ^ 1);

    f32x4 acc[2][4];
    #pragma unroll
    for (int m = 0; m < 2; ++m)
      #pragma unroll
      for (int n = 0; n < 4; ++n) acc[m][n] = (f32x4){0.f, 0.f, 0.f, 0.f};

    #pragma unroll
    for (int kt = 0; kt < KT; ++kt) {
      #pragma unroll
      for (int n = 0; n < 4; ++n) {
        const int boff = (n * 16 + (lane & 15)) * LDB + kt * 16 + (lane >> 4) * 4;
        uint4 u = *(const uint4*)&Bs[buf][boff];
        bf16x8 b8 = *reinterpret_cast<bf16x8*>(&u);
        acc[0][n] = __builtin_amdgcn_mfma_f32_16x16x32_bf16(a[0][kt], b8, acc[0][n], 0, 0, 0);
        acc[1][n] = __builtin_amdgcn_mfma_f32_16x16x32_bf16(a[1][kt], b8, acc[1][n], 0, 0, 0);
      }
    }

    ushort* ob; int stride, cbase, relu = 0;
    if (cb < nk)            { ob = kb; stride = nk; cbase = cb; }
    else if (cb < 2 * nk)   { ob = vb; stride = nk; cbase = cb - nk; }
    else                    { ob = qb; stride = nq; cbase = cb - 2 * nk; relu = reluq; }
    #pragma unroll
    for (int m = 0; m < 2; ++m) {
      const int rw = m0 + wv * 32 + m * 16 + (lane >> 4) * 4;
      #pragma unroll
      for (int n = 0; n < 4; ++n) {
        const int col = cbase + n * 16 + (lane & 15);
        #pragma unroll
        for (int j = 0; j < 4; ++j) {
          if (rw + j < M) {
            float o = acc[m][n][j];
            if (relu) o = fmaxf(o, 0.f);
            ob[(size_t)(rw + j) * stride + col] = f2bf(o);
          }
        }
      }
    }
    __syncthreads();
    buf ^= 1;
  }
}

// ---------------- split-bf16 persistent-A GEMM (3 MFMA/tile), fp32 out -------
template<int KT>
__global__ __launch_bounds__(256) void gemm_sp3(
    const ushort* __restrict__ Ah, const ushort* __restrict__ Al,
    const ushort* __restrict__ Bth, const ushort* __restrict__ Btl,
    int M, int NTOT, float* __restrict__ of)
{
  constexpr int K = KT * 32;
  constexpr int LDB = KT * 16 + 4;
  __shared__ uint Bh[64 * LDB];
  __shared__ uint Bl[64 * LDB];
  const int tid = threadIdx.x;
  const int m0 = blockIdx.x * 128;
  const int lane = tid & 63, wv = tid >> 6;
  const int rbase = m0 + wv * 32 + (lane & 15);
  const int kof = (lane >> 4) * 8;

  bf16x8 ah[2][KT], al[2][KT];
  #pragma unroll
  for (int m = 0; m < 2; ++m) {
    const int row = rbase + m * 16;
    #pragma unroll
    for (int kt = 0; kt < KT; ++kt) {
      uint4 uh = make_uint4(0, 0, 0, 0), ul = make_uint4(0, 0, 0, 0);
      if (row < M) {
        uh = *(const uint4*)(Ah + (size_t)row * K + kt * 32 + kof);
        ul = *(const uint4*)(Al + (size_t)row * K + kt * 32 + kof);
      }
      ah[m][kt] = *reinterpret_cast<bf16x8*>(&uh);
      al[m][kt] = *reinterpret_cast<bf16x8*>(&ul);
    }
  }

  for (int cb = 0; cb < NTOT; cb += 64) {
    {
      const int c = tid >> 2, kq = tid & 3;
      if (kq * 32 < K) {
        const uint4* sh = (const uint4*)(Bth + (size_t)(cb + c) * K + kq * 32);
        const uint4* sl = (const uint4*)(Btl + (size_t)(cb + c) * K + kq * 32);
        uint4* dh = (uint4*)&Bh[c * LDB + kq * 16];
        uint4* dl = (uint4*)&Bl[c * LDB + kq * 16];
        #pragma unroll
        for (int q = 0; q < 4; ++q) { dh[q] = sh[q]; dl[q] = sl[q]; }
      }
    }
    __syncthreads();

    f32x4 acc[2][4];
    #pragma unroll
    for (int m = 0; m < 2; ++m)
      #pragma unroll
      for (int n = 0; n < 4; ++n) acc[m][n] = (f32x4){0.f, 0.f, 0.f, 0.f};

    #pragma unroll
    for (int kt = 0; kt < KT; ++kt) {
      #pragma unroll
      for (int n = 0; n < 4; ++n) {
        const int boff = (n * 16 + (lane & 15)) * LDB + kt * 16 + (lane >> 4) * 4;
        uint4 uh = *(const uint4*)&Bh[boff];
        uint4 ul = *(const uint4*)&Bl[boff];
        bf16x8 bh = *reinterpret_cast<bf16x8*>(&uh);
        bf16x8 bl = *reinterpret_cast<bf16x8*>(&ul);
        #pragma unroll
        for (int m = 0; m < 2; ++m) {
          acc[m][n] = __builtin_amdgcn_mfma_f32_16x16x32_bf16(ah[m][kt], bh, acc[m][n], 0, 0, 0);
          acc[m][n] = __builtin_amdgcn_mfma_f32_16x16x32_bf16(ah[m][kt], bl, acc[m][n], 0, 0, 0);
          acc[m][n] = __builtin_amdgcn_mfma_f32_16x16x32_bf16(al[m][kt], bh, acc[m][n], 0, 0, 0);
        }
      }
    }

    #pragma unroll
    for (int m = 0; m < 2; ++m) {
      const int rw = m0 + wv * 32 + m * 16 + (lane >> 4) * 4;
      #pragma unroll
      for (int n = 0; n < 4; ++n) {
        const int col = cb + n * 16 + (lane & 15);
        #pragma unroll
        for (int j = 0; j < 4; ++j)
          if (rw + j < M) of[(size_t)(rw + j) * NTOT + col] = acc[m][n][j];
      }
    }
    __syncthreads();
  }
}

// ---------------- CSR build ----------------
__global__ __launch_bounds__(256) void csr_count(
    const int* __restrict__ EI, int* __restrict__ cnt)
{
  int idx = blockIdx.x * 256 + threadIdx.x;
  if (idx >= ETOT) return;
  int r = idx / EE, e = idx % EE;
  int dst = clampi(EI[(size_t)r * 2 * EE + EE + e], 0, NN - 1);
  atomicAdd(&cnt[dst], 1);
}

__global__ __launch_bounds__(256) void scan_intra(
    int* __restrict__ arr, int* __restrict__ blksum)
{
  __shared__ int s[256];
  const int t = threadIdx.x;
  const int i = blockIdx.x * 256 + t;
  int v = (i < NN) ? arr[i] : 0;
  s[t] = v;
  __syncthreads();
  #pragma unroll
  for (int off = 1; off < 256; off <<= 1) {
    int x = (t >= off) ? s[t - off] : 0;
    __syncthreads();
    s[t] += x;
    __syncthreads();
  }
  if (i < NN) arr[i] = s[t] - v;        // exclusive
  if (t == 255) blksum[blockIdx.x] = s[255];
}

__global__ __launch_bounds__(256) void scan_mid(
    const int* __restrict__ blksum, int* __restrict__ blkoff)
{
  __shared__ int s[256];
  __shared__ int carry;
  const int t = threadIdx.x;
  if (t == 0) carry = 0;
  __syncthreads();
  for (int base = 0; base < NB; base += 256) {
    const int i = base + t;
    int v = (i < NB) ? blksum[i] : 0;
    s[t] = v;
    __syncthreads();
    #pragma unroll
    for (int off = 1; off < 256; off <<= 1) {
      int x = (t >= off) ? s[t - off] : 0;
      __syncthreads();
      s[t] += x;
      __syncthreads();
    }
    if (i < NB) blkoff[i] = carry + s[t] - v;   // global exclusive
    __syncthreads();
    if (t == 255) carry += s[255];
    __syncthreads();
  }
}

__global__ __launch_bounds__(256) void scan_add(
    int* __restrict__ arr, const int* __restrict__ blkoff,
    int* __restrict__ rowptr, int* __restrict__ cursor)
{
  int i = blockIdx.x * 256 + threadIdx.x;
  if (i < NN) {
    int v = arr[i] + blkoff[i >> 8];
    rowptr[i] = v;
    cursor[i] = v;
  }
  if (i == NN) rowptr[NN] = ETOT;
}

__global__ __launch_bounds__(256) void csr_scatter(
    const int* __restrict__ EI, int* __restrict__ cursor,
    int* __restrict__ srcrel)
{
  int idx = blockIdx.x * 256 + threadIdx.x;
  if (idx >= ETOT) return;
  int r = idx / EE, e = idx % EE;
  int src = clampi(EI[(size_t)r * 2 * EE + e], 0, NN - 1);
  int dst = clampi(EI[(size_t)r * 2 * EE + EE + e], 0, NN - 1);
  int pos = atomicAdd(&cursor[dst], 1);
  pos = clampi(pos, 0, ETOT - 1);
  srcrel[pos] = src | (r << 24);
}

// ---------------- fused per-node score+softmax+aggregate ----------
// Edge-slot waves + UNROLL-2: per loop iter, 2 edge batches -> 4x 8B gathers +
// 2 srcrel reads in flight (round-15 counters: latency-bound at 2 in flight).
// kb/vb planar bf16 [N][RR*D] (prior/scale folded into kb); qb planar bf16.
// Clamps on srcrel-derived indices are load-bearing (r5/6, r12/13) — keep.
template<int D, int DH>
__global__ __launch_bounds__(256) void node_fused(
    const ushort* __restrict__ kb, const ushort* __restrict__ vb,
    const ushort* __restrict__ qb,
    const int* __restrict__ rowptr, const int* __restrict__ srcrel,
    ushort* __restrict__ agh, ushort* __restrict__ agl)
{
  constexpr int LPS = D / 4;        // lanes per edge slot (32 / 16)
  constexpr int ES  = 64 / LPS;     // edge slots per wave (2 / 4)
  constexpr int SUB = DH / 4;       // lanes per head in a slot (8 / 4)
  const int lane = threadIdx.x & 63;
  const int wv = threadIdx.x >> 6;
  const int n = blockIdx.x * 4 + wv;
  if (n >= NN) return;
  const int slot = lane / LPS;
  const int sl   = lane % LPS;      // features [4sl, 4sl+4)
  const uint2 qu = *(const uint2*)&qb[(size_t)n * D + sl * 4];
  const float q0 = __uint_as_float(qu.x << 16);
  const float q1 = __uint_as_float(qu.x & 0xFFFF0000u);
  const float q2 = __uint_as_float(qu.y << 16);
  const float q3 = __uint_as_float(qu.y & 0xFFFF0000u);
  const int j0 = clampi(rowptr[n], 0, ETOT);
  const int j1 = clampi(rowptr[n + 1], j0, ETOT);
  float a0 = 0.f, a1 = 0.f, a2 = 0.f, a3 = 0.f, den = 0.f;

  for (int jb = j0; jb < j1; jb += 2 * ES) {
    const int jA = jb + slot;
    const int jB = jb + ES + slot;
    const bool vA = jA < j1, vB = jB < j1;
    const int jjA = clampi(vA ? jA : j0, 0, ETOT - 1);
    const int jjB = clampi(vB ? jB : j0, 0, ETOT - 1);
    const int wA = srcrel[jjA];
    const int wB = srcrel[jjB];
    const int sA = clampi(wA & 0xFFFFFF, 0, NN - 1);
    const int rA = clampi(wA >> 24, 0, RR - 1);
    const int sB = clampi(wB & 0xFFFFFF, 0, NN - 1);
    const int rB = clampi(wB >> 24, 0, RR - 1);
    const size_t bA = (size_t)sA * (RR * D) + rA * D + sl * 4;
    const size_t bB = (size_t)sB * (RR * D) + rB * D + sl * 4;
    const uint2 kuA = *(const uint2*)&kb[bA];
    const uint2 vuA = *(const uint2*)&vb[bA];
    const uint2 kuB = *(const uint2*)&kb[bB];
    const uint2 vuB = *(const uint2*)&vb[bB];
    float sa =        __uint_as_float(kuA.x << 16)         * q0;
    sa = fmaf(__uint_as_float(kuA.x & 0xFFFF0000u), q1, sa);
    sa = fmaf(__uint_as_float(kuA.y << 16),         q2, sa);
    sa = fmaf(__uint_as_float(kuA.y & 0xFFFF0000u), q3, sa);
    float sb =        __uint_as_float(kuB.x << 16)         * q0;
    sb = fmaf(__uint_as_float(kuB.x & 0xFFFF0000u), q1, sb);
    sb = fmaf(__uint_as_float(kuB.y << 16),         q2, sb);
    sb = fmaf(__uint_as_float(kuB.y & 0xFFFF0000u), q3, sb);
    #pragma unroll
    for (int off = SUB / 2; off >= 1; off >>= 1) {
      sa += __shfl_xor(sa, off, 64);
      sb += __shfl_xor(sb, off, 64);
    }
    const float exA = vA ? __expf(sa) : 0.f;   // prior*scale folded into kb
    const float exB = vB ? __expf(sb) : 0.f;
    den += exA + exB;
    a0 = fmaf(exA, __uint_as_float(vuA.x << 16),         a0);
    a1 = fmaf(exA, __uint_as_float(vuA.x & 0xFFFF0000u), a1);
    a2 = fmaf(exA, __uint_as_float(vuA.y << 16),         a2);
    a3 = fmaf(exA, __uint_as_float(vuA.y & 0xFFFF0000u), a3);
    a0 = fmaf(exB, __uint_as_float(vuB.x << 16),         a0);
    a1 = fmaf(exB, __uint_as_float(vuB.x & 0xFFFF0000u), a1);
    a2 = fmaf(exB, __uint_as_float(vuB.y << 16),         a2);
    a3 = fmaf(exB, __uint_as_float(vuB.y & 0xFFFF0000u), a3);
  }

  // cross-slot combine (slots hold partial sums for the SAME node)
  #pragma unroll
  for (int off = LPS; off < 64; off <<= 1) {
    den += __shfl_xor(den, off, 64);
    a0 += __shfl_xor(a0, off, 64);
    a1 += __shfl_xor(a1, off, 64);
    a2 += __shfl_xor(a2, off, 64);
    a3 += __shfl_xor(a3, off, 64);
  }

  if (slot == 0) {
    const float inv = 1.f / (den + 1e-9f);
    const float o0 = a0 * inv, o1 = a1 * inv, o2 = a2 * inv, o3 = a3 * inv;
    if (agl) {
      ushort h0, l0, h1, l1, h2, l2, h3, l3;
      split2(o0, h0, l0); split2(o1, h1, l1);
      split2(o2, h2, l2); split2(o3, h3, l3);
      uint2 ho = make_uint2((uint)h0 | ((uint)h1 << 16), (uint)h2 | ((uint)h3 << 16));
      uint2 lo = make_uint2((uint)l0 | ((uint)l1 << 16), (uint)l2 | ((uint)l3 << 16));
      *(uint2*)&agh[(size_t)n * D + sl * 4] = ho;
      *(uint2*)&agl[(size_t)n * D + sl * 4] = lo;
    } else {
      uint2 ho = make_uint2((uint)f2bf(o0) | ((uint)f2bf(o1) << 16),
                            (uint)f2bf(o2) | ((uint)f2bf(o3) << 16));
      *(uint2*)&agh[(size_t)n * D + sl * 4] = ho;
    }
  }
}

extern "C" void kernel_launch(void* const* d_in, const int* in_sizes, int n_in,
                              void* d_out, int out_size, void* d_ws, size_t ws_size,
                              hipStream_t stream)
{
  const float* x   = (const float*)d_in[0];
  const int*   EI  = (const int*)  d_in[1];
  const float* Wk1 = (const float*)d_in[2];
  const float* Wq1 = (const float*)d_in[3];
  const float* Wv1 = (const float*)d_in[4];
  const float* A1  = (const float*)d_in[5];
  const float* M1  = (const float*)d_in[6];
  const float* P1  = (const float*)d_in[7];
  const float* Wo1 = (const float*)d_in[8];
  const float* Wk2 = (const float*)d_in[9];
  const float* Wq2 = (const float*)d_in[10];
  const float* Wv2 = (const float*)d_in[11];
  const float* A2  = (const float*)d_in[12];
  const float* M2  = (const float*)d_in[13];
  const float* P2  = (const float*)d_in[14];
  const float* Wo2 = (const float*)d_in[15];
  float* out = (float*)d_out;

  float* ws = (float*)d_ws;
  const size_t nd = (size_t)NN * 128;
  // ---- layout (round-14 proven core; WB arena enlarged to 1536 cols) ----
  ushort* xh   = (ushort*)ws;
  ushort* agh  = xh;
  ushort* qb2  = (ushort*)ws;                      // [0, nd/4)
  ushort* ag2h = (ushort*)(ws + nd / 4);           // [nd/4, nd/2)
  ushort* qb1  = (ushort*)(ws + nd / 2);           // [nd/2, nd)
  ushort* ag2l = (ushort*)(ws + nd / 2);           // [nd/2, 3nd/4) (qb1 dead)
  ushort* kb   = (ushort*)(ws + nd);
  ushort* vb   = (ushort*)(ws + 5 * nd / 2);
  ushort* Hbh  = (ushort*)(ws + 4 * nd);
  ushort* WBth = (ushort*)(ws + 5 * nd);           // 1536*128 ushorts
  ushort* WBtl = WBth + 1536 * 128;
  int* ints   = (int*)(WBtl + 1536 * 128);         // = ws + 5*nd + 98304 dwords... (1536*128 = 196608 ush = 98304 fl per plane)
  int* rowptr = ints;              // NN+1
  int* cursor = rowptr + NN + 1;   // NN
  int* blks   = cursor + NN;       // 2*NB
  int* srcrel = blks + 2 * NB;     // ETOT (src | r<<24, dst-sorted)

  const size_t need_bytes = (5 * nd + 2 * 98304) * 4 +
      ((size_t)(NN + 1) + NN + 2 * NB + ETOT) * 4;
  if (ws_size < need_bytes) return;   // visible absmax failure, not a fault

  dim3 blk(256);
  const int GB = (NN + 127) / 128;    // 782 row-blocks
  const int NFB = (NN + 3) / 4;       // node_fused blocks (1 node/wave)

  // ---------- 1: all prep in one full-width dispatch ----------
  prep_all<<<dim3(PREP_BLOCKS), blk, 0, stream>>>(
      x, xh, Wk1, A1, P1, Wv1, M1, Wq1, Wo1,
      Wk2, A2, P2, Wv2, M2, Wq2, Wo2, WBth, WBtl, cursor);

  // ---------- 2: Layer 1 mega bf16 GEMM (kA|vM|q) ----------
  gemm_bf1<4><<<dim3(GB), blk, 0, stream>>>(xh, WBth, NN, 896, kb, 384, vb, qb1, 128, 0);

  // ---------- 3-7: CSR build ----------
  csr_count<<<dim3((ETOT + 255) / 256), blk, 0, stream>>>(EI, cursor);
  scan_intra<<<dim3(NB), blk, 0, stream>>>(cursor, blks);
  scan_mid<<<dim3(1), blk, 0, stream>>>(blks, blks + NB);
  scan_add<<<dim3(NB), blk, 0, stream>>>(cursor, blks + NB, rowptr, cursor);
  csr_scatter<<<dim3((ETOT + 255) / 256), blk, 0, stream>>>(EI, cursor, srcrel);

  // ---------- 8-9: Layer 1 edge + Wo1 ----------
  node_fused<128, 32><<<dim3(NFB), blk, 0, stream>>>(
      kb, vb, qb1, rowptr, srcrel, agh, (ushort*)nullptr);
  gemm_bf1<4><<<dim3(GB), blk, 0, stream>>>(agh, WBth + 896 * 128, NN, 128,
                                            (ushort*)nullptr, 0, (ushort*)nullptr,
                                            Hbh, 128, 1);   // relu

  // ---------- 10: Layer 2 mega bf16 GEMM ----------
  gemm_bf1<4><<<dim3(GB), blk, 0, stream>>>(Hbh, WBth + 1024 * 128, NN, 448,
                                            kb, 192, vb, qb2, 64, 0);

  // ---------- 11-12: Layer 2 edge + Wo2 ----------
  node_fused<64, 16><<<dim3(NFB), blk, 0, stream>>>(
      kb, vb, qb2, rowptr, srcrel, ag2h, ag2l);
  gemm_sp3<2><<<dim3(GB), blk, 0, stream>>>(ag2h, ag2l,
                                            WBth + 1472 * 128, WBtl + 1472 * 128,
                                            NN, 64, out);
}

// Round 17
// 295.590 us; speedup vs baseline: 1.2300x; 1.0271x over previous
//
#include <hip/hip_runtime.h>

#define NN 100000
#define RR 3
#define EE 200000
#define HH 4
#define ETOT (RR * EE)
#define NB ((NN + 255) / 256)

typedef __attribute__((ext_vector_type(8))) short bf16x8;
typedef __attribute__((ext_vector_type(4))) float f32x4;

__device__ __forceinline__ int clampi(int v, int lo, int hi) {
  return v < lo ? lo : (v > hi ? hi : v);
}

__device__ __forceinline__ void split2(float v, ushort& h, ushort& l) {
  uint u = __float_as_uint(v);
  uint hb = (u + 0x7FFFu + ((u >> 16) & 1u)) >> 16;
  float fh = __uint_as_float(hb << 16);
  float r = v - fh;
  uint ur = __float_as_uint(r);
  uint lb = (ur + 0x7FFFu + ((ur >> 16) & 1u)) >> 16;
  h = (ushort)hb; l = (ushort)lb;
}

__device__ __forceinline__ ushort f2bf(float v) {
  uint u = __float_as_uint(v);
  return (ushort)((u + 0x7FFFu + ((u >> 16) & 1u)) >> 16);
}

// ---------------- prep bodies (device) ----------------
__device__ __forceinline__ void to_bf16_body(
    const float* __restrict__ A, ushort* __restrict__ Ah, int blk, int total8)
{
  int idx = blk * 256 + threadIdx.x;
  if (idx >= total8) return;
  const float4* ap = (const float4*)(A + (size_t)idx * 8);
  float4 a0 = ap[0], a1 = ap[1];
  const float v[8] = {a0.x, a0.y, a0.z, a0.w, a1.x, a1.y, a1.z, a1.w};
  ushort h[8];
  #pragma unroll
  for (int i = 0; i < 8; ++i) h[i] = f2bf(v[i]);
  *(uint4*)(Ah + (size_t)idx * 8) = *(const uint4*)h;
}

__device__ __forceinline__ void build_wT_body(
    const float* __restrict__ W, const float* __restrict__ T,
    ushort* __restrict__ Oh, ushort* __restrict__ Ol, int F, int D, int dh,
    const float* __restrict__ prior, float scale, int blk)
{
  const int cols = RR * D;
  int idx = blk * 256 + threadIdx.x;
  if (idx >= F * cols) return;
  int i = idx / cols, c = idx % cols;
  int r = c / D, gf = c % D;
  int h = gf / dh, f = gf % dh;
  const float* w = W + (size_t)i * D + h * dh;
  const float* t = T + ((size_t)(r * HH + h) * dh) * dh + f;
  float s = 0.f;
  for (int d = 0; d < dh; ++d) s = fmaf(w[d], t[(size_t)d * dh], s);
  if (prior) s *= prior[r * HH + h] * scale;
  ushort hh, ll; split2(s, hh, ll);
  Oh[(size_t)c * F + i] = hh;
  Ol[(size_t)c * F + i] = ll;
}

__device__ __forceinline__ void convt_body(
    const float* __restrict__ W, ushort* __restrict__ Th, ushort* __restrict__ Tl,
    int K, int N, int blk)
{
  int idx = blk * 256 + threadIdx.x;
  if (idx >= K * N) return;
  int n = idx / K, k = idx % K;
  ushort h, l; split2(W[(size_t)k * N + n], h, l);
  Th[(size_t)n * K + k] = h;
  Tl[(size_t)n * K + k] = l;
}

// ---------------- prep_all: x->bf16, cursor zero, ALL weight builds ----------
// WB column map: [0,384) kA1 | [384,768) vM1 | [768,896) q1 | [896,1024) Wo1 |
// [1024,1216) kA2 | [1216,1408) vM2 | [1408,1472) q2 | [1472,1536) Wo2
__global__ __launch_bounds__(256) void prep_all(
    const float* __restrict__ x, ushort* __restrict__ xh,
    const float* __restrict__ Wk1, const float* __restrict__ A1, const float* __restrict__ P1,
    const float* __restrict__ Wv1, const float* __restrict__ M1,
    const float* __restrict__ Wq1, const float* __restrict__ Wo1,
    const float* __restrict__ Wk2, const float* __restrict__ A2, const float* __restrict__ P2,
    const float* __restrict__ Wv2, const float* __restrict__ M2,
    const float* __restrict__ Wq2, const float* __restrict__ Wo2,
    ushort* __restrict__ WBth, ushort* __restrict__ WBtl, int* __restrict__ cursor)
{
  int b = blockIdx.x;
  if (b < 6250) { to_bf16_body(x, xh, b, NN * 128 / 8); return; }
  b -= 6250;
  if (b < NB) { int i = b * 256 + threadIdx.x; if (i < NN) cursor[i] = 0; return; }
  b -= NB;
  if (b < 192) { build_wT_body(Wk1, A1, WBth, WBtl, 128, 128, 32, P1, 0.17677669529663687f, b); return; }
  b -= 192;
  if (b < 192) { build_wT_body(Wv1, M1, WBth + 384 * 128, WBtl + 384 * 128, 128, 128, 32, (const float*)0, 1.f, b); return; }
  b -= 192;
  if (b < 64) { convt_body(Wq1, WBth + 768 * 128, WBtl + 768 * 128, 128, 128, b); return; }
  b -= 64;
  if (b < 64) { convt_body(Wo1, WBth + 896 * 128, WBtl + 896 * 128, 128, 128, b); return; }
  b -= 64;
  if (b < 96) { build_wT_body(Wk2, A2, WBth + 1024 * 128, WBtl + 1024 * 128, 128, 64, 16, P2, 0.25f, b); return; }
  b -= 96;
  if (b < 96) { build_wT_body(Wv2, M2, WBth + 1216 * 128, WBtl + 1216 * 128, 128, 64, 16, (const float*)0, 1.f, b); return; }
  b -= 96;
  if (b < 32) { convt_body(Wq2, WBth + 1408 * 128, WBtl + 1408 * 128, 128, 64, b); return; }
  b -= 32;
  if (b < 16) { convt_body(Wo2, WBth + 1472 * 128, WBtl + 1472 * 128, 64, 64, b); return; }
}
#define PREP_BLOCKS (6250 + NB + 192 + 192 + 64 + 64 + 96 + 96 + 32 + 16)

// ---------------- pure-bf16 persistent-A GEMM (1 MFMA/tile), y-sliced -------
// blockIdx.y slices the column-chunk range (round-16 counters: 782 blocks ->
// 24% occupancy was the limiter; y=2 doubles resident waves).
template<int KT>   // K = KT*32
__global__ __launch_bounds__(256) void gemm_bf1(
    const ushort* __restrict__ Ah, const ushort* __restrict__ Bth,
    int M, int NTOT,
    ushort* __restrict__ kb, int nk, ushort* __restrict__ vb,
    ushort* __restrict__ qb, int nq, int reluq)
{
  constexpr int K = KT * 32;
  constexpr int LDB = KT * 16 + 4;
  __shared__ uint Bs[2][64 * LDB];
  const int tid = threadIdx.x;
  const int m0 = blockIdx.x * 128;

  const int nch = NTOT >> 6;
  const int ych = (nch + gridDim.y - 1) / gridDim.y;
  const int c0 = blockIdx.y * ych * 64;
  int c1 = c0 + ych * 64; if (c1 > NTOT) c1 = NTOT;
  if (c0 >= c1) return;

  const int lane = tid & 63, wv = tid >> 6;
  const int rbase = m0 + wv * 32 + (lane & 15);
  const int kof = (lane >> 4) * 8;

  bf16x8 a[2][KT];
  #pragma unroll
  for (int m = 0; m < 2; ++m) {
    const int row = rbase + m * 16;
    #pragma unroll
    for (int kt = 0; kt < KT; ++kt) {
      uint4 u = make_uint4(0, 0, 0, 0);
      if (row < M) u = *(const uint4*)(Ah + (size_t)row * K + kt * 32 + kof);
      a[m][kt] = *reinterpret_cast<bf16x8*>(&u);
    }
  }

  auto stage = [&](int cb, int b) {
    const int c = tid >> 2, kq = tid & 3;
    if (kq * 32 < K) {
      const uint4* s = (const uint4*)(Bth + (size_t)(cb + c) * K + kq * 32);
      uint4* d = (uint4*)&Bs[b][c * LDB + kq * 16];
      #pragma unroll
      for (int q = 0; q < 4; ++q) d[q] = s[q];
    }
  };
  stage(c0, 0);
  __syncthreads();
  int buf = 0;

  for (int cb = c0; cb < c1; cb += 64) {
    if (cb + 64 < c1) stage(cb + 64, buf ^ 1);

    f32x4 acc[2][4];
    #pragma unroll
    for (int m = 0; m < 2; ++m)
      #pragma unroll
      for (int n = 0; n < 4; ++n) acc[m][n] = (f32x4){0.f, 0.f, 0.f, 0.f};

    #pragma unroll
    for (int kt = 0; kt < KT; ++kt) {
      #pragma unroll
      for (int n = 0; n < 4; ++n) {
        const int boff = (n * 16 + (lane & 15)) * LDB + kt * 16 + (lane >> 4) * 4;
        uint4 u = *(const uint4*)&Bs[buf][boff];
        bf16x8 b8 = *reinterpret_cast<bf16x8*>(&u);
        acc[0][n] = __builtin_amdgcn_mfma_f32_16x16x32_bf16(a[0][kt], b8, acc[0][n], 0, 0, 0);
        acc[1][n] = __builtin_amdgcn_mfma_f32_16x16x32_bf16(a[1][kt], b8, acc[1][n], 0, 0, 0);
      }
    }

    ushort* ob; int stride, cbase, relu = 0;
    if (cb < nk)            { ob = kb; stride = nk; cbase = cb; }
    else if (cb < 2 * nk)   { ob = vb; stride = nk; cbase = cb - nk; }
    else                    { ob = qb; stride = nq; cbase = cb - 2 * nk; relu = reluq; }
    #pragma unroll
    for (int m = 0; m < 2; ++m) {
      const int rw = m0 + wv * 32 + m * 16 + (lane >> 4) * 4;
      #pragma unroll
      for (int n = 0; n < 4; ++n) {
        const int col = cbase + n * 16 + (lane & 15);
        #pragma unroll
        for (int j = 0; j < 4; ++j) {
          if (rw + j < M) {
            float o = acc[m][n][j];
            if (relu) o = fmaxf(o, 0.f);
            ob[(size_t)(rw + j) * stride + col] = f2bf(o);
          }
        }
      }
    }
    __syncthreads();
    buf ^= 1;
  }
}

// ---------------- split-bf16 persistent-A GEMM (3 MFMA/tile), fp32 out -------
template<int KT>
__global__ __launch_bounds__(256) void gemm_sp3(
    const ushort* __restrict__ Ah, const ushort* __restrict__ Al,
    const ushort* __restrict__ Bth, const ushort* __restrict__ Btl,
    int M, int NTOT, float* __restrict__ of)
{
  constexpr int K = KT * 32;
  constexpr int LDB = KT * 16 + 4;
  __shared__ uint Bh[64 * LDB];
  __shared__ uint Bl[64 * LDB];
  const int tid = threadIdx.x;
  const int m0 = blockIdx.x * 128;
  const int lane = tid & 63, wv = tid >> 6;
  const int rbase = m0 + wv * 32 + (lane & 15);
  const int kof = (lane >> 4) * 8;

  bf16x8 ah[2][KT], al[2][KT];
  #pragma unroll
  for (int m = 0; m < 2; ++m) {
    const int row = rbase + m * 16;
    #pragma unroll
    for (int kt = 0; kt < KT; ++kt) {
      uint4 uh = make_uint4(0, 0, 0, 0), ul = make_uint4(0, 0, 0, 0);
      if (row < M) {
        uh = *(const uint4*)(Ah + (size_t)row * K + kt * 32 + kof);
        ul = *(const uint4*)(Al + (size_t)row * K + kt * 32 + kof);
      }
      ah[m][kt] = *reinterpret_cast<bf16x8*>(&uh);
      al[m][kt] = *reinterpret_cast<bf16x8*>(&ul);
    }
  }

  for (int cb = 0; cb < NTOT; cb += 64) {
    {
      const int c = tid >> 2, kq = tid & 3;
      if (kq * 32 < K) {
        const uint4* sh = (const uint4*)(Bth + (size_t)(cb + c) * K + kq * 32);
        const uint4* sl = (const uint4*)(Btl + (size_t)(cb + c) * K + kq * 32);
        uint4* dh = (uint4*)&Bh[c * LDB + kq * 16];
        uint4* dl = (uint4*)&Bl[c * LDB + kq * 16];
        #pragma unroll
        for (int q = 0; q < 4; ++q) { dh[q] = sh[q]; dl[q] = sl[q]; }
      }
    }
    __syncthreads();

    f32x4 acc[2][4];
    #pragma unroll
    for (int m = 0; m < 2; ++m)
      #pragma unroll
      for (int n = 0; n < 4; ++n) acc[m][n] = (f32x4){0.f, 0.f, 0.f, 0.f};

    #pragma unroll
    for (int kt = 0; kt < KT; ++kt) {
      #pragma unroll
      for (int n = 0; n < 4; ++n) {
        const int boff = (n * 16 + (lane & 15)) * LDB + kt * 16 + (lane >> 4) * 4;
        uint4 uh = *(const uint4*)&Bh[boff];
        uint4 ul = *(const uint4*)&Bl[boff];
        bf16x8 bh = *reinterpret_cast<bf16x8*>(&uh);
        bf16x8 bl = *reinterpret_cast<bf16x8*>(&ul);
        #pragma unroll
        for (int m = 0; m < 2; ++m) {
          acc[m][n] = __builtin_amdgcn_mfma_f32_16x16x32_bf16(ah[m][kt], bh, acc[m][n], 0, 0, 0);
          acc[m][n] = __builtin_amdgcn_mfma_f32_16x16x32_bf16(ah[m][kt], bl, acc[m][n], 0, 0, 0);
          acc[m][n] = __builtin_amdgcn_mfma_f32_16x16x32_bf16(al[m][kt], bh, acc[m][n], 0, 0, 0);
        }
      }
    }

    #pragma unroll
    for (int m = 0; m < 2; ++m) {
      const int rw = m0 + wv * 32 + m * 16 + (lane >> 4) * 4;
      #pragma unroll
      for (int n = 0; n < 4; ++n) {
        const int col = cb + n * 16 + (lane & 15);
        #pragma unroll
        for (int j = 0; j < 4; ++j)
          if (rw + j < M) of[(size_t)(rw + j) * NTOT + col] = acc[m][n][j];
      }
    }
    __syncthreads();
  }
}

// ---------------- CSR build ----------------
__global__ __launch_bounds__(256) void csr_count(
    const int* __restrict__ EI, int* __restrict__ cnt)
{
  int idx = blockIdx.x * 256 + threadIdx.x;
  if (idx >= ETOT) return;
  int r = idx / EE, e = idx % EE;
  int dst = clampi(EI[(size_t)r * 2 * EE + EE + e], 0, NN - 1);
  atomicAdd(&cnt[dst], 1);
}

__global__ __launch_bounds__(256) void scan_intra(
    int* __restrict__ arr, int* __restrict__ blksum)
{
  __shared__ int s[256];
  const int t = threadIdx.x;
  const int i = blockIdx.x * 256 + t;
  int v = (i < NN) ? arr[i] : 0;
  s[t] = v;
  __syncthreads();
  #pragma unroll
  for (int off = 1; off < 256; off <<= 1) {
    int x = (t >= off) ? s[t - off] : 0;
    __syncthreads();
    s[t] += x;
    __syncthreads();
  }
  if (i < NN) arr[i] = s[t] - v;        // exclusive
  if (t == 255) blksum[blockIdx.x] = s[255];
}

__global__ __launch_bounds__(256) void scan_mid(
    const int* __restrict__ blksum, int* __restrict__ blkoff)
{
  __shared__ int s[256];
  __shared__ int carry;
  const int t = threadIdx.x;
  if (t == 0) carry = 0;
  __syncthreads();
  for (int base = 0; base < NB; base += 256) {
    const int i = base + t;
    int v = (i < NB) ? blksum[i] : 0;
    s[t] = v;
    __syncthreads();
    #pragma unroll
    for (int off = 1; off < 256; off <<= 1) {
      int x = (t >= off) ? s[t - off] : 0;
      __syncthreads();
      s[t] += x;
      __syncthreads();
    }
    if (i < NB) blkoff[i] = carry + s[t] - v;   // global exclusive
    __syncthreads();
    if (t == 255) carry += s[255];
    __syncthreads();
  }
}

__global__ __launch_bounds__(256) void scan_add(
    int* __restrict__ arr, const int* __restrict__ blkoff,
    int* __restrict__ rowptr, int* __restrict__ cursor)
{
  int i = blockIdx.x * 256 + threadIdx.x;
  if (i < NN) {
    int v = arr[i] + blkoff[i >> 8];
    rowptr[i] = v;
    cursor[i] = v;
  }
  if (i == NN) rowptr[NN] = ETOT;
}

__global__ __launch_bounds__(256) void csr_scatter(
    const int* __restrict__ EI, int* __restrict__ cursor,
    int* __restrict__ srcrel)
{
  int idx = blockIdx.x * 256 + threadIdx.x;
  if (idx >= ETOT) return;
  int r = idx / EE, e = idx % EE;
  int src = clampi(EI[(size_t)r * 2 * EE + e], 0, NN - 1);
  int dst = clampi(EI[(size_t)r * 2 * EE + EE + e], 0, NN - 1);
  int pos = atomicAdd(&cursor[dst], 1);
  pos = clampi(pos, 0, ETOT - 1);
  srcrel[pos] = src | (r << 24);
}

// ---------------- fused per-node score+softmax+aggregate ----------
// Edge-slot waves, UNR edge batches per iter -> 2*UNR*ES 8B gathers in flight.
// kb/vb planar bf16 [N][RR*D] (prior/scale folded into kb); qb planar bf16.
// Clamps on srcrel-derived indices are load-bearing (r5/6, r12/13) — keep.
template<int D, int DH, int UNR>
__global__ __launch_bounds__(256) void node_fused(
    const ushort* __restrict__ kb, const ushort* __restrict__ vb,
    const ushort* __restrict__ qb,
    const int* __restrict__ rowptr, const int* __restrict__ srcrel,
    ushort* __restrict__ agh, ushort* __restrict__ agl)
{
  constexpr int LPS = D / 4;        // lanes per edge slot (32 / 16)
  constexpr int ES  = 64 / LPS;     // edge slots per wave (2 / 4)
  constexpr int SUB = DH / 4;       // lanes per head in a slot (8 / 4)
  const int lane = threadIdx.x & 63;
  const int wv = threadIdx.x >> 6;
  const int n = blockIdx.x * 4 + wv;
  if (n >= NN) return;
  const int slot = lane / LPS;
  const int sl   = lane % LPS;      // features [4sl, 4sl+4)
  const uint2 qu = *(const uint2*)&qb[(size_t)n * D + sl * 4];
  const float q0 = __uint_as_float(qu.x << 16);
  const float q1 = __uint_as_float(qu.x & 0xFFFF0000u);
  const float q2 = __uint_as_float(qu.y << 16);
  const float q3 = __uint_as_float(qu.y & 0xFFFF0000u);
  const int j0 = clampi(rowptr[n], 0, ETOT);
  const int j1 = clampi(rowptr[n + 1], j0, ETOT);
  float a0 = 0.f, a1 = 0.f, a2 = 0.f, a3 = 0.f, den = 0.f;

  for (int jb = j0; jb < j1; jb += UNR * ES) {
    bool vv[UNR];
    int w[UNR];
    #pragma unroll
    for (int u = 0; u < UNR; ++u) {
      const int j = jb + u * ES + slot;
      vv[u] = j < j1;
      const int jj = clampi(vv[u] ? j : j0, 0, ETOT - 1);
      w[u] = srcrel[jj];
    }
    uint2 ku[UNR], vu[UNR];
    #pragma unroll
    for (int u = 0; u < UNR; ++u) {
      const int si = clampi(w[u] & 0xFFFFFF, 0, NN - 1);
      const int r  = clampi(w[u] >> 24, 0, RR - 1);
      const size_t b = (size_t)si * (RR * D) + r * D + sl * 4;
      ku[u] = *(const uint2*)&kb[b];
      vu[u] = *(const uint2*)&vb[b];
    }
    float s[UNR];
    #pragma unroll
    for (int u = 0; u < UNR; ++u) {
      float t =        __uint_as_float(ku[u].x << 16)         * q0;
      t = fmaf(__uint_as_float(ku[u].x & 0xFFFF0000u), q1, t);
      t = fmaf(__uint_as_float(ku[u].y << 16),         q2, t);
      t = fmaf(__uint_as_float(ku[u].y & 0xFFFF0000u), q3, t);
      s[u] = t;
    }
    #pragma unroll
    for (int off = SUB / 2; off >= 1; off >>= 1)
      #pragma unroll
      for (int u = 0; u < UNR; ++u) s[u] += __shfl_xor(s[u], off, 64);
    #pragma unroll
    for (int u = 0; u < UNR; ++u) {
      const float ex = vv[u] ? __expf(s[u]) : 0.f;   // prior*scale folded in kb
      den += ex;
      a0 = fmaf(ex, __uint_as_float(vu[u].x << 16),         a0);
      a1 = fmaf(ex, __uint_as_float(vu[u].x & 0xFFFF0000u), a1);
      a2 = fmaf(ex, __uint_as_float(vu[u].y << 16),         a2);
      a3 = fmaf(ex, __uint_as_float(vu[u].y & 0xFFFF0000u), a3);
    }
  }

  // cross-slot combine (slots hold partial sums for the SAME node)
  #pragma unroll
  for (int off = LPS; off < 64; off <<= 1) {
    den += __shfl_xor(den, off, 64);
    a0 += __shfl_xor(a0, off, 64);
    a1 += __shfl_xor(a1, off, 64);
    a2 += __shfl_xor(a2, off, 64);
    a3 += __shfl_xor(a3, off, 64);
  }

  if (slot == 0) {
    const float inv = 1.f / (den + 1e-9f);
    const float o0 = a0 * inv, o1 = a1 * inv, o2 = a2 * inv, o3 = a3 * inv;
    if (agl) {
      ushort h0, l0, h1, l1, h2, l2, h3, l3;
      split2(o0, h0, l0); split2(o1, h1, l1);
      split2(o2, h2, l2); split2(o3, h3, l3);
      uint2 ho = make_uint2((uint)h0 | ((uint)h1 << 16), (uint)h2 | ((uint)h3 << 16));
      uint2 lo = make_uint2((uint)l0 | ((uint)l1 << 16), (uint)l2 | ((uint)l3 << 16));
      *(uint2*)&agh[(size_t)n * D + sl * 4] = ho;
      *(uint2*)&agl[(size_t)n * D + sl * 4] = lo;
    } else {
      uint2 ho = make_uint2((uint)f2bf(o0) | ((uint)f2bf(o1) << 16),
                            (uint)f2bf(o2) | ((uint)f2bf(o3) << 16));
      *(uint2*)&agh[(size_t)n * D + sl * 4] = ho;
    }
  }
}

extern "C" void kernel_launch(void* const* d_in, const int* in_sizes, int n_in,
                              void* d_out, int out_size, void* d_ws, size_t ws_size,
                              hipStream_t stream)
{
  const float* x   = (const float*)d_in[0];
  const int*   EI  = (const int*)  d_in[1];
  const float* Wk1 = (const float*)d_in[2];
  const float* Wq1 = (const float*)d_in[3];
  const float* Wv1 = (const float*)d_in[4];
  const float* A1  = (const float*)d_in[5];
  const float* M1  = (const float*)d_in[6];
  const float* P1  = (const float*)d_in[7];
  const float* Wo1 = (const float*)d_in[8];
  const float* Wk2 = (const float*)d_in[9];
  const float* Wq2 = (const float*)d_in[10];
  const float* Wv2 = (const float*)d_in[11];
  const float* A2  = (const float*)d_in[12];
  const float* M2  = (const float*)d_in[13];
  const float* P2  = (const float*)d_in[14];
  const float* Wo2 = (const float*)d_in[15];
  float* out = (float*)d_out;

  float* ws = (float*)d_ws;
  const size_t nd = (size_t)NN * 128;
  // ---- layout identical to round 16 (proven) ----
  ushort* xh   = (ushort*)ws;
  ushort* agh  = xh;
  ushort* qb2  = (ushort*)ws;                      // [0, nd/4)
  ushort* ag2h = (ushort*)(ws + nd / 4);           // [nd/4, nd/2)
  ushort* qb1  = (ushort*)(ws + nd / 2);           // [nd/2, nd)
  ushort* ag2l = (ushort*)(ws + nd / 2);           // [nd/2, 3nd/4) (qb1 dead)
  ushort* kb   = (ushort*)(ws + nd);
  ushort* vb   = (ushort*)(ws + 5 * nd / 2);
  ushort* Hbh  = (ushort*)(ws + 4 * nd);
  ushort* WBth = (ushort*)(ws + 5 * nd);           // 1536*128 ushorts
  ushort* WBtl = WBth + 1536 * 128;
  int* ints   = (int*)(WBtl + 1536 * 128);
  int* rowptr = ints;              // NN+1
  int* cursor = rowptr + NN + 1;   // NN
  int* blks   = cursor + NN;       // 2*NB
  int* srcrel = blks + 2 * NB;     // ETOT (src | r<<24, dst-sorted)

  const size_t need_bytes = (5 * nd + 2 * 98304) * 4 +
      ((size_t)(NN + 1) + NN + 2 * NB + ETOT) * 4;
  if (ws_size < need_bytes) return;   // visible absmax failure, not a fault

  dim3 blk(256);
  const int GB = (NN + 127) / 128;    // 782 row-blocks
  const int NFB = (NN + 3) / 4;       // node_fused blocks (1 node/wave)

  // ---------- 1: all prep in one full-width dispatch ----------
  prep_all<<<dim3(PREP_BLOCKS), blk, 0, stream>>>(
      x, xh, Wk1, A1, P1, Wv1, M1, Wq1, Wo1,
      Wk2, A2, P2, Wv2, M2, Wq2, Wo2, WBth, WBtl, cursor);

  // ---------- 2: Layer 1 mega bf16 GEMM (kA|vM|q), y-split 2 ----------
  gemm_bf1<4><<<dim3(GB, 2), blk, 0, stream>>>(xh, WBth, NN, 896, kb, 384, vb, qb1, 128, 0);

  // ---------- 3-7: CSR build ----------
  csr_count<<<dim3((ETOT + 255) / 256), blk, 0, stream>>>(EI, cursor);
  scan_intra<<<dim3(NB), blk, 0, stream>>>(cursor, blks);
  scan_mid<<<dim3(1), blk, 0, stream>>>(blks, blks + NB);
  scan_add<<<dim3(NB), blk, 0, stream>>>(cursor, blks + NB, rowptr, cursor);
  csr_scatter<<<dim3((ETOT + 255) / 256), blk, 0, stream>>>(EI, cursor, srcrel);

  // ---------- 8-9: Layer 1 edge + Wo1 ----------
  node_fused<128, 32, 4><<<dim3(NFB), blk, 0, stream>>>(
      kb, vb, qb1, rowptr, srcrel, agh, (ushort*)nullptr);
  gemm_bf1<4><<<dim3(GB, 2), blk, 0, stream>>>(agh, WBth + 896 * 128, NN, 128,
                                               (ushort*)nullptr, 0, (ushort*)nullptr,
                                               Hbh, 128, 1);   // relu

  // ---------- 10: Layer 2 mega bf16 GEMM, y-split 2 ----------
  gemm_bf1<4><<<dim3(GB, 2), blk, 0, stream>>>(Hbh, WBth + 1024 * 128, NN, 448,
                                               kb, 192, vb, qb2, 64, 0);

  // ---------- 11-12: Layer 2 edge + Wo2 ----------
  node_fused<64, 16, 2><<<dim3(NFB), blk, 0, stream>>>(
      kb, vb, qb2, rowptr, srcrel, ag2h, ag2l);
  gemm_sp3<2><<<dim3(GB), blk, 0, stream>>>(ag2h, ag2l,
                                            WBth + 1472 * 128, WBtl + 1472 * 128,
                                            NN, 64, out);
}